// Round 3
// baseline (373.403 us; speedup 1.0000x reference)
//
#include <hip/hip_runtime.h>
#include <hip/hip_bf16.h>

#define EPS 1e-5f

// ws layout (floats):
#define WS_W1AT 0        // W1a[:, :64] transposed: [j*64 + c]
#define WS_W1BT 4096     // W1b transposed:        [j*64 + c]
#define WS_WSKT 8192     // Wskip[:, :64] transposed
#define WS_A0   12288    // (N,K,C): W0[:, :64] @ scene_rgb
#define WS_C1A  20480    // (N,K,C): W1a[:, 64:67] @ (scene_xyz*mask)
#define WS_CSK  28672    // (N,K,C): Wskip[:, 64:67] @ (scene_xyz*mask)
#define WS_BN   36864    // s0,t0 | s1a,t1a | s1b,t1b  (3 layers * 128)
// total 37248 floats = 149 KB

__global__ __launch_bounds__(256) void prep_wb(
    const float* __restrict__ W1a, const float* __restrict__ W1b, const float* __restrict__ Wskip,
    const float* __restrict__ g0, const float* __restrict__ b0, const float* __restrict__ m0, const float* __restrict__ v0,
    const float* __restrict__ g1a, const float* __restrict__ b1a, const float* __restrict__ m1a, const float* __restrict__ v1a,
    const float* __restrict__ g1b, const float* __restrict__ b1b, const float* __restrict__ m1b, const float* __restrict__ v1b,
    float* __restrict__ ws)
{
    int idx = blockIdx.x * 256 + threadIdx.x;
    if (idx < 4096) {
        int j = idx >> 6, c = idx & 63;
        ws[WS_W1AT + idx] = W1a[c * 67 + j];
        ws[WS_W1BT + idx] = W1b[c * 64 + j];
        ws[WS_WSKT + idx] = Wskip[c * 67 + j];
    }
    if (idx < 192) {
        int layer = idx >> 6, c = idx & 63;
        const float *g, *b, *m, *v;
        if (layer == 0)      { g = g0;  b = b0;  m = m0;  v = v0;  }
        else if (layer == 1) { g = g1a; b = b1a; m = m1a; v = v1a; }
        else                 { g = g1b; b = b1b; m = m1b; v = v1b; }
        float s = g[c] * rsqrtf(v[c] + EPS);
        float t = b[c] - m[c] * s;
        ws[WS_BN + layer * 128 + c] = s;
        ws[WS_BN + layer * 128 + 64 + c] = t;
    }
}

__global__ __launch_bounds__(256) void prep_nk(
    const float* __restrict__ scene_rgb,  // (N,C,K)
    const float* __restrict__ scene_xyz,  // (N,3,K)
    const float* __restrict__ mask,       // (N,K)
    const float* __restrict__ W0,         // (C,128)
    const float* __restrict__ W1a,        // (C,67)
    const float* __restrict__ Wskip,      // (C,67)
    float* __restrict__ ws)
{
    int idx = blockIdx.x * 256 + threadIdx.x;   // (n,k,c)
    if (idx >= 2 * 64 * 64) return;
    int c = idx & 63;
    int k = (idx >> 6) & 63;
    int n = idx >> 12;
    float a = 0.f;
    #pragma unroll
    for (int j = 0; j < 64; ++j)
        a += W0[c * 128 + j] * scene_rgb[(n * 64 + j) * 64 + k];
    ws[WS_A0 + idx] = a;
    float mk = mask[n * 64 + k];
    float x0 = scene_xyz[(n * 3 + 0) * 64 + k] * mk;
    float x1 = scene_xyz[(n * 3 + 1) * 64 + k] * mk;
    float x2 = scene_xyz[(n * 3 + 2) * 64 + k] * mk;
    ws[WS_C1A + idx] = W1a[c * 67 + 64] * x0 + W1a[c * 67 + 65] * x1 + W1a[c * 67 + 66] * x2;
    ws[WS_CSK + idx] = Wskip[c * 67 + 64] * x0 + Wskip[c * 67 + 65] * x1 + Wskip[c * 67 + 66] * x2;
}

#define LDS_STRIDE 65   // (l*65 + j) % 32 = (l + j) % 32 -> 2 lanes/bank = conflict-free

__global__ __launch_bounds__(64) void ctx_main(
    const float* __restrict__ q,       // (N,C,M)
    const float* __restrict__ prexyz,  // (N,3,M)
    const float* __restrict__ W0,      // (C,128)
    const float* __restrict__ Wout,    // (3,67)
    const float* __restrict__ ws,
    float* __restrict__ out)           // (N,3,M) fp32
{
    const int m = blockIdx.x;
    const int n = blockIdx.y;
    const int lane = threadIdx.x;       // lane = k, and channel role for B-compute

    const float* W1aT = ws + WS_W1AT;
    const float* W1bT = ws + WS_W1BT;
    const float* WskT = ws + WS_WSKT;
    const float* BN   = ws + WS_BN;

    __shared__ float qs[64];
    __shared__ float bs[64];
    __shared__ float hl[64 * LDS_STRIDE];

    qs[lane] = q[(n * 64 + lane) * 4800 + m];
    __syncthreads();

    // B[c=lane] = sum_j W0[c][64+j] * q[j]   (query half of fcn0)
    {
        float acc = 0.f;
        const float* wr = W0 + lane * 128 + 64;
        #pragma unroll
        for (int j = 0; j < 64; ++j) acc += wr[j] * qs[j];
        bs[lane] = acc;
    }
    __syncthreads();

    const int k = lane;
    const int nk = (n * 64 + k) * 64;

    // h = relu(bn0(A0(n,k) + B(n,m)))  -> LDS
    {
        const float* a0 = ws + WS_A0 + nk;
        #pragma unroll
        for (int c = 0; c < 64; ++c) {
            float pre = a0[c] + bs[c];
            float h = fmaxf(BN[c] * pre + BN[64 + c], 0.f);
            hl[lane * LDS_STRIDE + c] = h;
        }
    }
    __syncthreads();

    float acc1[64];
    float feat[64];
    {
        const float* c1 = ws + WS_C1A + nk;
        const float* cs = ws + WS_CSK + nk;
        #pragma unroll
        for (int c = 0; c < 64; ++c) { acc1[c] = c1[c]; feat[c] = cs[c]; }
        // stage 1 (W1a) + skip (Wskip), both consume h: outer j rolled,
        // inner c unrolled -> accumulators stay in registers, weights are
        // wave-uniform -> s_load broadcasts.
        #pragma unroll 1
        for (int j = 0; j < 64; ++j) {
            float hj = hl[lane * LDS_STRIDE + j];
            const float* w1 = W1aT + j * 64;
            const float* wk = WskT + j * 64;
            #pragma unroll
            for (int c = 0; c < 64; ++c) {
                acc1[c] = fmaf(w1[c], hj, acc1[c]);
                feat[c] = fmaf(wk[c], hj, feat[c]);
            }
        }
    }
    __syncthreads();
    // h1 = relu(bn1a(acc1)) -> LDS (reuse hl)
    #pragma unroll
    for (int c = 0; c < 64; ++c) {
        float h1 = fmaxf(BN[128 + c] * acc1[c] + BN[192 + c], 0.f);
        hl[lane * LDS_STRIDE + c] = h1;
    }
    __syncthreads();

    // stage 2 (W1b), then feat += relu(bn1b(.))
    {
        float acc2[64];
        #pragma unroll
        for (int c = 0; c < 64; ++c) acc2[c] = 0.f;
        #pragma unroll 1
        for (int j = 0; j < 64; ++j) {
            float hj = hl[lane * LDS_STRIDE + j];
            const float* w2 = W1bT + j * 64;
            #pragma unroll
            for (int c = 0; c < 64; ++c)
                acc2[c] = fmaf(w2[c], hj, acc2[c]);
        }
        #pragma unroll
        for (int c = 0; c < 64; ++c)
            feat[c] += fmaxf(BN[256 + c] * acc2[c] + BN[320 + c], 0.f);
    }

    // max over k (= lanes), then out = Wout @ [featmax; pre_xyz]
    float o0 = 0.f, o1 = 0.f, o2 = 0.f;
    #pragma unroll
    for (int c = 0; c < 64; ++c) {
        float v = feat[c];
        #pragma unroll
        for (int off = 32; off > 0; off >>= 1)
            v = fmaxf(v, __shfl_xor(v, off));
        o0 += Wout[c] * v;
        o1 += Wout[67 + c] * v;
        o2 += Wout[134 + c] * v;
    }
    if (lane < 3) {
        float p0 = prexyz[(n * 3 + 0) * 4800 + m];
        float p1 = prexyz[(n * 3 + 1) * 4800 + m];
        float p2 = prexyz[(n * 3 + 2) * 4800 + m];
        float o = (lane == 0) ? o0 : ((lane == 1) ? o1 : o2);
        const float* wo = Wout + lane * 67 + 64;
        o += wo[0] * p0 + wo[1] * p1 + wo[2] * p2;
        out[(n * 3 + lane) * 4800 + m] = o;   // fp32 store — the R2 bug was bf16-converting here
    }
}

extern "C" void kernel_launch(void* const* d_in, const int* in_sizes, int n_in,
                              void* d_out, int out_size, void* d_ws, size_t ws_size,
                              hipStream_t stream) {
    const float* q    = (const float*)d_in[0];
    const float* srgb = (const float*)d_in[1];
    const float* sxyz = (const float*)d_in[2];
    const float* pxyz = (const float*)d_in[3];
    const float* mask = (const float*)d_in[4];
    const float* W0   = (const float*)d_in[5];
    const float* g0   = (const float*)d_in[6];
    const float* b0   = (const float*)d_in[7];
    const float* m0   = (const float*)d_in[8];
    const float* v0   = (const float*)d_in[9];
    const float* W1a  = (const float*)d_in[10];
    const float* g1a  = (const float*)d_in[11];
    const float* b1a  = (const float*)d_in[12];
    const float* m1a  = (const float*)d_in[13];
    const float* v1a  = (const float*)d_in[14];
    const float* W1b  = (const float*)d_in[15];
    const float* g1b  = (const float*)d_in[16];
    const float* b1b  = (const float*)d_in[17];
    const float* m1b  = (const float*)d_in[18];
    const float* v1b  = (const float*)d_in[19];
    const float* Wsk  = (const float*)d_in[20];
    const float* Wout = (const float*)d_in[21];
    float* ws  = (float*)d_ws;
    float* out = (float*)d_out;

    hipLaunchKernelGGL(prep_wb, dim3(16), dim3(256), 0, stream,
        W1a, W1b, Wsk, g0, b0, m0, v0, g1a, b1a, m1a, v1a, g1b, b1b, m1b, v1b, ws);
    hipLaunchKernelGGL(prep_nk, dim3(32), dim3(256), 0, stream,
        srgb, sxyz, mask, W0, W1a, Wsk, ws);
    hipLaunchKernelGGL(ctx_main, dim3(4800, 2), dim3(64), 0, stream,
        q, pxyz, W0, Wout, ws, out);
}

// Round 4
// 147.832 us; speedup vs baseline: 2.5259x; 2.5259x over previous
//
#include <hip/hip_runtime.h>

typedef unsigned int   u32;
typedef unsigned short u16;
typedef float f32x4  __attribute__((ext_vector_type(4)));
typedef short bf16x8 __attribute__((ext_vector_type(8)));
typedef u32   u32x4  __attribute__((ext_vector_type(4)));
typedef u32   u32x2  __attribute__((ext_vector_type(2)));

#define EPS 1e-5f
#define MT 4800

// ws layout (bytes):
//   WF    @ 0      : 32 frags x 64 lanes x 16B = 32768   (fi = g3*8 + ct*2 + t; g3: 0=W1a 1=Wskip 2=W1b 3=W0q)
//   STAGE @ 32768  : per n: 13824 u16 = { A0'[64k][72c] | C1T[64c][72k] | CST[64c][72k] } , 2 n = 55296 B
// total 88064 B (proven ws_size >= 149KB in R0-R3)

__device__ __forceinline__ u32 f2bf(float f) {
    union { float f; u32 i; } x; x.f = f;
    return (x.i + 0x7fffu + ((x.i >> 16) & 1u)) >> 16;
}
__device__ __forceinline__ u32 pk2(float lo, float hi) { return f2bf(lo) | (f2bf(hi) << 16); }
__device__ __forceinline__ float bflo(u32 p) { union { u32 i; float f; } x; x.i = p << 16; return x.f; }
__device__ __forceinline__ float bfhi(u32 p) { union { u32 i; float f; } x; x.i = p & 0xffff0000u; return x.f; }

union UU { u32x4 u; bf16x8 b; };

// ---------------- prep: weight fragments (bf16, MFMA B-operand layout) ----------------
__global__ __launch_bounds__(256) void prep_w(
    const float* __restrict__ W1a, const float* __restrict__ Wsk,
    const float* __restrict__ W1b, const float* __restrict__ W0,
    u32* __restrict__ wf)
{
    int idx = blockIdx.x * 256 + threadIdx.x;   // 0..2047
    int fi = idx >> 6, l = idx & 63;
    int g3 = fi >> 3, ct = (fi >> 1) & 3, t = fi & 1;
    int c  = ct * 16 + (l & 15);                // B-frag: col = lane&15
    int j0 = t * 32 + (l >> 4) * 8;             // k = 8*(lane>>4) + e  (+32*t)
    float v[8];
    #pragma unroll
    for (int e = 0; e < 8; ++e) {
        int j = j0 + e;
        float x;
        if      (g3 == 0) x = W1a[c * 67 + j];
        else if (g3 == 1) x = Wsk[c * 67 + j];
        else if (g3 == 2) x = W1b[c * 64 + j];
        else              x = W0[c * 128 + 64 + j];   // query half of fcn0
        v[e] = x;
    }
    u32x4 p;
    p[0] = pk2(v[0], v[1]); p[1] = pk2(v[2], v[3]);
    p[2] = pk2(v[4], v[5]); p[3] = pk2(v[6], v[7]);
    ((u32x4*)wf)[idx] = p;
}

// ---------------- prep: per-(n,k) folded tensors, bf16 ----------------
__global__ __launch_bounds__(256) void prep_nk(
    const float* __restrict__ srgb, const float* __restrict__ sxyz, const float* __restrict__ mask,
    const float* __restrict__ W0,   const float* __restrict__ W1a,  const float* __restrict__ Wsk,
    const float* __restrict__ g0, const float* __restrict__ b0, const float* __restrict__ m0_, const float* __restrict__ v0_,
    const float* __restrict__ g1a, const float* __restrict__ b1a, const float* __restrict__ m1a, const float* __restrict__ v1a,
    u16* __restrict__ stg)
{
    int idx = blockIdx.x * 256 + threadIdx.x;   // 0..8191 : (n,k,c)
    int c = idx & 63, k = (idx >> 6) & 63, n = idx >> 12;
    float dot = 0.f;
    #pragma unroll
    for (int j = 0; j < 64; ++j)
        dot += W0[c * 128 + j] * srgb[(n * 64 + j) * 64 + k];
    float s0 = g0[c] * rsqrtf(v0_[c] + EPS);
    float t0 = b0[c] - m0_[c] * s0;
    u16* base = stg + n * 13824;
    base[k * 72 + c] = (u16)f2bf(s0 * dot + t0);              // A0' = s0*A0 + t0

    float mk = mask[n * 64 + k];
    float x0 = sxyz[(n * 3 + 0) * 64 + k] * mk;
    float x1 = sxyz[(n * 3 + 1) * 64 + k] * mk;
    float x2 = sxyz[(n * 3 + 2) * 64 + k] * mk;
    float s1a = g1a[c] * rsqrtf(v1a[c] + EPS);
    float t1a = b1a[c] - m1a[c] * s1a;
    float c1 = W1a[c * 67 + 64] * x0 + W1a[c * 67 + 65] * x1 + W1a[c * 67 + 66] * x2;
    base[4608 + c * 72 + k] = (u16)f2bf(s1a * c1 + t1a);      // C1'' = s1a*C1A + t1a  (transposed [c][k])
    float cs = Wsk[c * 67 + 64] * x0 + Wsk[c * 67 + 65] * x1 + Wsk[c * 67 + 66] * x2;
    base[9216 + c * 72 + k] = (u16)f2bf(cs);                  // CSK (transposed [c][k])
}

// ---------------- main: 3-stage MFMA MLP + pool ----------------
__global__ __launch_bounds__(256) void ctx_mfma(
    const float* __restrict__ q, const float* __restrict__ prexyz,
    const float* __restrict__ g0, const float* __restrict__ v0_,
    const float* __restrict__ g1a, const float* __restrict__ v1a,
    const float* __restrict__ g1b, const float* __restrict__ v1b,
    const float* __restrict__ b1b, const float* __restrict__ m1b,
    const float* __restrict__ Wout,
    const u32* __restrict__ ws_u32,
    float* __restrict__ out)
{
    const int tid = threadIdx.x;
    const int w = tid >> 6, l = tid & 63;
    const int g = l >> 4, kidx = l & 15;
    const int mg = blockIdx.x, n = blockIdx.y;
    const int m0 = mg * 16;

    __shared__ u16  stage[13824];      // A0'[64][72] | C1T[64][72] | CST[64][72]
    __shared__ u16  h1s[4][16 * 72];   // per-wave h1 repack scratch
    __shared__ float Bs[16 * 68];      // B' = s0 * (W0q @ q) for this block's 16 m

    // stage copy: 6912 u32 = 27 per thread
    {
        const u32* src = ws_u32 + 8192 + n * 6912;
        u32* dst = (u32*)stage;
        #pragma unroll
        for (int j2 = 0; j2 < 27; ++j2) dst[tid + 256 * j2] = src[tid + 256 * j2];
    }

    const u32x4* wfp = (const u32x4*)ws_u32;

    // resident weight fragments (B-operand layout)
    bf16x8 w1a[8], wsk[8], w1b[8];
    #pragma unroll
    for (int f = 0; f < 8; ++f) { UU x; x.u = wfp[(0 * 8 + f) * 64 + l]; w1a[f] = x.b; }
    #pragma unroll
    for (int f = 0; f < 8; ++f) { UU x; x.u = wfp[(1 * 8 + f) * 64 + l]; wsk[f] = x.b; }
    #pragma unroll
    for (int f = 0; f < 8; ++f) { UU x; x.u = wfp[(2 * 8 + f) * 64 + l]; w1b[f] = x.b; }

    // wave 0: B' GEMM  (rows = 16 m of this block, cols = 64 c, K = 64 q-channels)
    if (w == 0) {
        f32x4 acc0[4];
        #pragma unroll
        for (int ct = 0; ct < 4; ++ct) acc0[ct] = 0.f;
        #pragma unroll
        for (int t = 0; t < 2; ++t) {
            float qe[8];
            #pragma unroll
            for (int e = 0; e < 8; ++e)
                qe[e] = q[(n * 64 + t * 32 + g * 8 + e) * MT + m0 + kidx];
            UU a; a.u = (u32x4){pk2(qe[0], qe[1]), pk2(qe[2], qe[3]), pk2(qe[4], qe[5]), pk2(qe[6], qe[7])};
            #pragma unroll
            for (int ct = 0; ct < 4; ++ct) {
                UU wb; wb.u = wfp[(3 * 8 + ct * 2 + t) * 64 + l];
                acc0[ct] = __builtin_amdgcn_mfma_f32_16x16x32_bf16(a.b, wb.b, acc0[ct], 0, 0, 0);
            }
        }
        #pragma unroll
        for (int ct = 0; ct < 4; ++ct) {
            int c = ct * 16 + kidx;
            float s0 = g0[c] * rsqrtf(v0_[c] + EPS);
            #pragma unroll
            for (int r = 0; r < 4; ++r)
                Bs[(g * 4 + r) * 68 + c] = s0 * acc0[ct][r];   // row = m-in-block
        }
    }

    // per-lane folded BN / Wout scalars (c = 16*ct + kidx)
    float s1a_r[4], s1b_r[4], t1b_r[4], wo0[4], wo1[4], wo2[4];
    #pragma unroll
    for (int ct = 0; ct < 4; ++ct) {
        int c = ct * 16 + kidx;
        s1a_r[ct] = g1a[c] * rsqrtf(v1a[c] + EPS);
        float s1b = g1b[c] * rsqrtf(v1b[c] + EPS);
        s1b_r[ct] = s1b;
        t1b_r[ct] = b1b[c] - m1b[c] * s1b;
        wo0[ct] = Wout[0 * 67 + c];
        wo1[ct] = Wout[1 * 67 + c];
        wo2[ct] = Wout[2 * 67 + c];
    }

    __syncthreads();   // stage + Bs ready

    const u16* A0p = stage;          // [k][72]
    const u16* C1p = stage + 4608;   // [c][72]
    const u16* CSp = stage + 9216;   // [c][72]
    u16* h1p = h1s[w];

    #pragma unroll 1
    for (int i = 0; i < 4; ++i) {
        const int m = m0 + w * 4 + i;

        float bfr[2][8];
        #pragma unroll
        for (int t = 0; t < 2; ++t)
            #pragma unroll
            for (int e = 0; e < 8; ++e)
                bfr[t][e] = Bs[(w * 4 + i) * 68 + t * 32 + g * 8 + e];

        float fmr[4];
        #pragma unroll
        for (int ct = 0; ct < 4; ++ct) fmr[ct] = -3.0e38f;

        for (int s = 0; s < 4; ++s) {   // 4 strips of 16 k-points
            // h0 A-fragments built directly in fragment layout
            bf16x8 af[2];
            #pragma unroll
            for (int t = 0; t < 2; ++t) {
                u32x4 a = *(const u32x4*)(A0p + (s * 16 + kidx) * 72 + t * 32 + g * 8);
                float h[8];
                h[0] = bflo(a[0]); h[1] = bfhi(a[0]); h[2] = bflo(a[1]); h[3] = bfhi(a[1]);
                h[4] = bflo(a[2]); h[5] = bfhi(a[2]); h[6] = bflo(a[3]); h[7] = bfhi(a[3]);
                #pragma unroll
                for (int e = 0; e < 8; ++e) h[e] = fmaxf(h[e] + bfr[t][e], 0.f);
                UU x; x.u = (u32x4){pk2(h[0], h[1]), pk2(h[2], h[3]), pk2(h[4], h[5]), pk2(h[6], h[7])};
                af[t] = x.b;
            }
            // stage1 + skip GEMMs
            f32x4 acc1[4], accS[4];
            #pragma unroll
            for (int ct = 0; ct < 4; ++ct) { acc1[ct] = 0.f; accS[ct] = 0.f; }
            #pragma unroll
            for (int t = 0; t < 2; ++t)
                #pragma unroll
                for (int ct = 0; ct < 4; ++ct)
                    acc1[ct] = __builtin_amdgcn_mfma_f32_16x16x32_bf16(af[t], w1a[ct * 2 + t], acc1[ct], 0, 0, 0);
            #pragma unroll
            for (int t = 0; t < 2; ++t)
                #pragma unroll
                for (int ct = 0; ct < 4; ++ct)
                    accS[ct] = __builtin_amdgcn_mfma_f32_16x16x32_bf16(af[t], wsk[ct * 2 + t], accS[ct], 0, 0, 0);

            // h1 = relu(s1a*acc1 + C1'') -> per-wave LDS (D-layout -> A-layout repack)
            #pragma unroll
            for (int ct = 0; ct < 4; ++ct) {
                int c = ct * 16 + kidx;
                u32x2 cv = *(const u32x2*)(C1p + c * 72 + s * 16 + g * 4);
                float c1v[4] = {bflo(cv[0]), bfhi(cv[0]), bflo(cv[1]), bfhi(cv[1])};
                #pragma unroll
                for (int r = 0; r < 4; ++r) {
                    float h1v = fmaxf(s1a_r[ct] * acc1[ct][r] + c1v[r], 0.f);
                    h1p[(g * 4 + r) * 72 + c] = (u16)f2bf(h1v);
                }
            }
            // stage2 GEMM from repacked h1
            f32x4 acc2[4];
            #pragma unroll
            for (int ct = 0; ct < 4; ++ct) acc2[ct] = 0.f;
            #pragma unroll
            for (int t = 0; t < 2; ++t) {
                UU x; x.u = *(const u32x4*)(h1p + kidx * 72 + t * 32 + g * 8);
                #pragma unroll
                for (int ct = 0; ct < 4; ++ct)
                    acc2[ct] = __builtin_amdgcn_mfma_f32_16x16x32_bf16(x.b, w1b[ct * 2 + t], acc2[ct], 0, 0, 0);
            }
            // feat = accS + CSK + relu(s1b*acc2 + t1b);  running max over rows (k-points)
            #pragma unroll
            for (int ct = 0; ct < 4; ++ct) {
                int c = ct * 16 + kidx;
                u32x2 cv = *(const u32x2*)(CSp + c * 72 + s * 16 + g * 4);
                float csv[4] = {bflo(cv[0]), bfhi(cv[0]), bflo(cv[1]), bfhi(cv[1])};
                #pragma unroll
                for (int r = 0; r < 4; ++r) {
                    float f = accS[ct][r] + csv[r] + fmaxf(s1b_r[ct] * acc2[ct][r] + t1b_r[ct], 0.f);
                    fmr[ct] = fmaxf(fmr[ct], f);
                }
            }
        }

        // finish pool across lane groups, then out = Wout @ [featmax; prexyz]
        #pragma unroll
        for (int ct = 0; ct < 4; ++ct) {
            fmr[ct] = fmaxf(fmr[ct], __shfl_xor(fmr[ct], 16));
            fmr[ct] = fmaxf(fmr[ct], __shfl_xor(fmr[ct], 32));
        }
        float po0 = 0.f, po1 = 0.f, po2 = 0.f;
        #pragma unroll
        for (int ct = 0; ct < 4; ++ct) {
            po0 += wo0[ct] * fmr[ct];
            po1 += wo1[ct] * fmr[ct];
            po2 += wo2[ct] * fmr[ct];
        }
        #pragma unroll
        for (int d = 1; d <= 8; d <<= 1) {
            po0 += __shfl_xor(po0, d);
            po1 += __shfl_xor(po1, d);
            po2 += __shfl_xor(po2, d);
        }
        if (l < 3) {
            float p0 = prexyz[(n * 3 + 0) * MT + m];
            float p1 = prexyz[(n * 3 + 1) * MT + m];
            float p2 = prexyz[(n * 3 + 2) * MT + m];
            float o = (l == 0) ? po0 : ((l == 1) ? po1 : po2);
            o += Wout[l * 67 + 64] * p0 + Wout[l * 67 + 65] * p1 + Wout[l * 67 + 66] * p2;
            out[(n * 3 + l) * MT + m] = o;
        }
    }
}

extern "C" void kernel_launch(void* const* d_in, const int* in_sizes, int n_in,
                              void* d_out, int out_size, void* d_ws, size_t ws_size,
                              hipStream_t stream) {
    const float* q    = (const float*)d_in[0];
    const float* srgb = (const float*)d_in[1];
    const float* sxyz = (const float*)d_in[2];
    const float* pxyz = (const float*)d_in[3];
    const float* mask = (const float*)d_in[4];
    const float* W0   = (const float*)d_in[5];
    const float* g0   = (const float*)d_in[6];
    const float* b0   = (const float*)d_in[7];
    const float* m0   = (const float*)d_in[8];
    const float* v0   = (const float*)d_in[9];
    const float* W1a  = (const float*)d_in[10];
    const float* g1a  = (const float*)d_in[11];
    const float* b1a  = (const float*)d_in[12];
    const float* m1a  = (const float*)d_in[13];
    const float* v1a  = (const float*)d_in[14];
    const float* W1b  = (const float*)d_in[15];
    const float* g1b  = (const float*)d_in[16];
    const float* b1b  = (const float*)d_in[17];
    const float* m1b  = (const float*)d_in[18];
    const float* v1b  = (const float*)d_in[19];
    const float* Wsk  = (const float*)d_in[20];
    const float* Wout = (const float*)d_in[21];
    u32* ws = (u32*)d_ws;
    float* out = (float*)d_out;

    hipLaunchKernelGGL(prep_w, dim3(8), dim3(256), 0, stream, W1a, Wsk, W1b, W0, ws);
    hipLaunchKernelGGL(prep_nk, dim3(32), dim3(256), 0, stream,
        srgb, sxyz, mask, W0, W1a, Wsk,
        g0, b0, m0, v0, g1a, b1a, m1a, v1a,
        (u16*)(ws + 8192));
    hipLaunchKernelGGL(ctx_mfma, dim3(300, 2), dim3(256), 0, stream,
        q, pxyz, g0, v0, g1a, v1a, g1b, v1b, b1b, m1b, Wout, ws, out);
}

// Round 6
// 145.863 us; speedup vs baseline: 2.5600x; 1.0135x over previous
//
#include <hip/hip_runtime.h>

typedef unsigned int   u32;
typedef unsigned short u16;
typedef float f32x4  __attribute__((ext_vector_type(4)));
typedef short bf16x8 __attribute__((ext_vector_type(8)));
typedef u32   u32x4  __attribute__((ext_vector_type(4)));
typedef u32   u32x2  __attribute__((ext_vector_type(2)));

#define EPS 1e-5f
#define MT 4800

// single-instruction RNE pack of two f32 -> packed bf16x2 (T12 recipe; no builtin on gfx950)
__device__ __forceinline__ u32 cvtpk(float lo, float hi) {
    u32 r;
    asm("v_cvt_pk_bf16_f32 %0, %1, %2" : "=v"(r) : "v"(lo), "v"(hi));
    return r;
}
__device__ __forceinline__ float bflo(u32 p) { union { u32 i; float f; } x; x.i = p << 16; return x.f; }
__device__ __forceinline__ float bfhi(u32 p) { union { u32 i; float f; } x; x.i = p & 0xffff0000u; return x.f; }

union UU { u32x4 u; bf16x8 b; };

__device__ __forceinline__ bf16x8 pack8(const float* __restrict__ p) {
    UU x;
    x.u = (u32x4){cvtpk(p[0], p[1]), cvtpk(p[2], p[3]), cvtpk(p[4], p[5]), cvtpk(p[6], p[7])};
    return x.b;
}

__global__ __launch_bounds__(256) void ctx_fused(
    const float* __restrict__ q, const float* __restrict__ srgb,
    const float* __restrict__ sxyz, const float* __restrict__ prexyz,
    const float* __restrict__ mask,
    const float* __restrict__ W0,
    const float* __restrict__ g0, const float* __restrict__ b0,
    const float* __restrict__ m0_, const float* __restrict__ v0_,
    const float* __restrict__ W1a,
    const float* __restrict__ g1a, const float* __restrict__ b1a,
    const float* __restrict__ m1a, const float* __restrict__ v1a,
    const float* __restrict__ W1b,
    const float* __restrict__ g1b, const float* __restrict__ b1b,
    const float* __restrict__ m1b, const float* __restrict__ v1b,
    const float* __restrict__ Wsk, const float* __restrict__ Wout,
    float* __restrict__ out)
{
    const int tid = threadIdx.x;
    const int w = tid >> 6, l = tid & 63;
    const int g = l >> 4, kidx = l & 15;
    const int mg = blockIdx.x, n = blockIdx.y;
    const int m0 = mg * 16;

    __shared__ u16  stage[13824];      // A0'[64k][72c] | C1''[64c][72k] | CSK[64c][72k]
    __shared__ u16  h1s[4][16 * 72];   // per-wave h1 repack scratch
    __shared__ float Bs[16 * 68];      // B' = s0 * (W0q @ q) for this block's 16 m

    // ---- prep A: resident weight fragments, straight from global (L2-hot) ----
    bf16x8 w1a[8], wsk[8], w1b[8];
    #pragma unroll
    for (int f = 0; f < 8; ++f) {
        int ct = f >> 1, t = f & 1;
        int c  = ct * 16 + kidx;
        int j0 = t * 32 + g * 8;
        w1a[f] = pack8(W1a + c * 67 + j0);
        wsk[f] = pack8(Wsk + c * 67 + j0);
        w1b[f] = pack8(W1b + c * 64 + j0);
    }

    // ---- prep B: A0' = bn0-fold(W0rgb @ srgb[n]); wave w computes k-rows 16w..16w+15 ----
    {
        f32x4 acc[4];
        #pragma unroll
        for (int ct = 0; ct < 4; ++ct) acc[ct] = 0.f;
        #pragma unroll
        for (int t = 0; t < 2; ++t) {
            float se[8];
            #pragma unroll
            for (int e = 0; e < 8; ++e) {
                int j = t * 32 + g * 8 + e;
                se[e] = srgb[(n * 64 + j) * 64 + w * 16 + kidx];
            }
            UU a; a.u = (u32x4){cvtpk(se[0], se[1]), cvtpk(se[2], se[3]),
                                cvtpk(se[4], se[5]), cvtpk(se[6], se[7])};
            #pragma unroll
            for (int ct = 0; ct < 4; ++ct) {
                bf16x8 wb = pack8(W0 + (ct * 16 + kidx) * 128 + t * 32 + g * 8);
                acc[ct] = __builtin_amdgcn_mfma_f32_16x16x32_bf16(a.b, wb, acc[ct], 0, 0, 0);
            }
        }
        #pragma unroll
        for (int ct = 0; ct < 4; ++ct) {
            int c = ct * 16 + kidx;
            float s0 = g0[c] * rsqrtf(v0_[c] + EPS);
            float t0 = b0[c] - m0_[c] * s0;
            u32 p01 = cvtpk(s0 * acc[ct][0] + t0, s0 * acc[ct][1] + t0);
            u32 p23 = cvtpk(s0 * acc[ct][2] + t0, s0 * acc[ct][3] + t0);
            int kb = w * 16 + g * 4;
            stage[(kb + 0) * 72 + c] = (u16)p01;
            stage[(kb + 1) * 72 + c] = (u16)(p01 >> 16);
            stage[(kb + 2) * 72 + c] = (u16)p23;
            stage[(kb + 3) * 72 + c] = (u16)(p23 >> 16);
        }
    }

    // ---- prep C: C1'' and CSK (tid -> channel c, 16 consecutive k) ----
    {
        int c  = tid & 63;
        int kq = tid >> 6;
        float s1a = g1a[c] * rsqrtf(v1a[c] + EPS);
        float t1a = b1a[c] - m1a[c] * s1a;
        float wa0 = W1a[c * 67 + 64], wa1 = W1a[c * 67 + 65], wa2 = W1a[c * 67 + 66];
        float wsa = Wsk[c * 67 + 64], wsb = Wsk[c * 67 + 65], wsc = Wsk[c * 67 + 66];
        u32* d1 = (u32*)(stage + 4608 + c * 72 + kq * 16);
        u32* d2 = (u32*)(stage + 9216 + c * 72 + kq * 16);
        #pragma unroll
        for (int p = 0; p < 8; ++p) {
            float v[2], s[2];
            #pragma unroll
            for (int h = 0; h < 2; ++h) {
                int k = kq * 16 + p * 2 + h;
                float mk = mask[n * 64 + k];
                float x0 = sxyz[(n * 3 + 0) * 64 + k] * mk;
                float x1 = sxyz[(n * 3 + 1) * 64 + k] * mk;
                float x2 = sxyz[(n * 3 + 2) * 64 + k] * mk;
                v[h] = s1a * (wa0 * x0 + wa1 * x1 + wa2 * x2) + t1a;
                s[h] = wsa * x0 + wsb * x1 + wsc * x2;
            }
            d1[p] = cvtpk(v[0], v[1]);
            d2[p] = cvtpk(s[0], s[1]);
        }
    }

    // ---- prep D: wave 0: B' GEMM (16 m rows x 64 c, K = 64 q-channels) ----
    if (w == 0) {
        f32x4 acc0[4];
        #pragma unroll
        for (int ct = 0; ct < 4; ++ct) acc0[ct] = 0.f;
        #pragma unroll
        for (int t = 0; t < 2; ++t) {
            float qe[8];
            #pragma unroll
            for (int e = 0; e < 8; ++e)
                qe[e] = q[(n * 64 + t * 32 + g * 8 + e) * MT + m0 + kidx];
            UU a; a.u = (u32x4){cvtpk(qe[0], qe[1]), cvtpk(qe[2], qe[3]),
                                cvtpk(qe[4], qe[5]), cvtpk(qe[6], qe[7])};
            #pragma unroll
            for (int ct = 0; ct < 4; ++ct) {
                bf16x8 wb = pack8(W0 + (ct * 16 + kidx) * 128 + 64 + t * 32 + g * 8);
                acc0[ct] = __builtin_amdgcn_mfma_f32_16x16x32_bf16(a.b, wb, acc0[ct], 0, 0, 0);
            }
        }
        #pragma unroll
        for (int ct = 0; ct < 4; ++ct) {
            int c = ct * 16 + kidx;
            float s0 = g0[c] * rsqrtf(v0_[c] + EPS);
            #pragma unroll
            for (int r = 0; r < 4; ++r)
                Bs[(g * 4 + r) * 68 + c] = s0 * acc0[ct][r];
        }
    }

    // per-lane folded BN / Wout scalars (c = 16*ct + kidx)
    float s1a_r[4], s1b_r[4], t1b_r[4], wo0[4], wo1[4], wo2[4];
    #pragma unroll
    for (int ct = 0; ct < 4; ++ct) {
        int c = ct * 16 + kidx;
        s1a_r[ct] = g1a[c] * rsqrtf(v1a[c] + EPS);
        float s1b = g1b[c] * rsqrtf(v1b[c] + EPS);
        s1b_r[ct] = s1b;
        t1b_r[ct] = b1b[c] - m1b[c] * s1b;
        wo0[ct] = Wout[0 * 67 + c];
        wo1[ct] = Wout[1 * 67 + c];
        wo2[ct] = Wout[2 * 67 + c];
    }

    __syncthreads();   // stage + Bs ready

    const u16* A0p = stage;          // [k][72]
    const u16* C1p = stage + 4608;   // [c][72]
    const u16* CSp = stage + 9216;   // [c][72]
    u16* h1p = h1s[w];

    #pragma unroll 1
    for (int i = 0; i < 4; ++i) {
        const int m = m0 + w * 4 + i;

        float bfr[2][8];
        #pragma unroll
        for (int t = 0; t < 2; ++t)
            #pragma unroll
            for (int e = 0; e < 8; ++e)
                bfr[t][e] = Bs[(w * 4 + i) * 68 + t * 32 + g * 8 + e];

        float fmr[4];
        #pragma unroll
        for (int ct = 0; ct < 4; ++ct) fmr[ct] = -3.0e38f;

        for (int s = 0; s < 4; ++s) {   // 4 strips of 16 k-points
            // h0 A-fragments built directly in fragment layout
            bf16x8 af[2];
            #pragma unroll
            for (int t = 0; t < 2; ++t) {
                u32x4 a = *(const u32x4*)(A0p + (s * 16 + kidx) * 72 + t * 32 + g * 8);
                float h[8];
                h[0] = bflo(a[0]); h[1] = bfhi(a[0]); h[2] = bflo(a[1]); h[3] = bfhi(a[1]);
                h[4] = bflo(a[2]); h[5] = bfhi(a[2]); h[6] = bflo(a[3]); h[7] = bfhi(a[3]);
                #pragma unroll
                for (int e = 0; e < 8; ++e) h[e] = fmaxf(h[e] + bfr[t][e], 0.f);
                UU x; x.u = (u32x4){cvtpk(h[0], h[1]), cvtpk(h[2], h[3]),
                                    cvtpk(h[4], h[5]), cvtpk(h[6], h[7])};
                af[t] = x.b;
            }
            // stage1 + skip GEMMs
            f32x4 acc1[4], accS[4];
            #pragma unroll
            for (int ct = 0; ct < 4; ++ct) { acc1[ct] = 0.f; accS[ct] = 0.f; }
            #pragma unroll
            for (int t = 0; t < 2; ++t)
                #pragma unroll
                for (int ct = 0; ct < 4; ++ct)
                    acc1[ct] = __builtin_amdgcn_mfma_f32_16x16x32_bf16(af[t], w1a[ct * 2 + t], acc1[ct], 0, 0, 0);
            #pragma unroll
            for (int t = 0; t < 2; ++t)
                #pragma unroll
                for (int ct = 0; ct < 4; ++ct)
                    accS[ct] = __builtin_amdgcn_mfma_f32_16x16x32_bf16(af[t], wsk[ct * 2 + t], accS[ct], 0, 0, 0);

            // h1 = relu(s1a*acc1 + C1'') -> per-wave LDS (D-layout -> A-layout repack)
            #pragma unroll
            for (int ct = 0; ct < 4; ++ct) {
                int c = ct * 16 + kidx;
                u32x2 cv = *(const u32x2*)(C1p + c * 72 + s * 16 + g * 4);
                float c1v[4] = {bflo(cv[0]), bfhi(cv[0]), bflo(cv[1]), bfhi(cv[1])};
                float hv[4];
                #pragma unroll
                for (int r = 0; r < 4; ++r)
                    hv[r] = fmaxf(s1a_r[ct] * acc1[ct][r] + c1v[r], 0.f);
                u32 p01 = cvtpk(hv[0], hv[1]);
                u32 p23 = cvtpk(hv[2], hv[3]);
                h1p[(g * 4 + 0) * 72 + c] = (u16)p01;
                h1p[(g * 4 + 1) * 72 + c] = (u16)(p01 >> 16);
                h1p[(g * 4 + 2) * 72 + c] = (u16)p23;
                h1p[(g * 4 + 3) * 72 + c] = (u16)(p23 >> 16);
            }
            // stage2 GEMM from repacked h1
            f32x4 acc2[4];
            #pragma unroll
            for (int ct = 0; ct < 4; ++ct) acc2[ct] = 0.f;
            #pragma unroll
            for (int t = 0; t < 2; ++t) {
                UU x; x.u = *(const u32x4*)(h1p + kidx * 72 + t * 32 + g * 8);
                #pragma unroll
                for (int ct = 0; ct < 4; ++ct)
                    acc2[ct] = __builtin_amdgcn_mfma_f32_16x16x32_bf16(x.b, w1b[ct * 2 + t], acc2[ct], 0, 0, 0);
            }
            // feat = accS + CSK + relu(s1b*acc2 + t1b);  running max over rows (k-points)
            #pragma unroll
            for (int ct = 0; ct < 4; ++ct) {
                int c = ct * 16 + kidx;
                u32x2 cv = *(const u32x2*)(CSp + c * 72 + s * 16 + g * 4);
                float csv[4] = {bflo(cv[0]), bfhi(cv[0]), bflo(cv[1]), bfhi(cv[1])};
                #pragma unroll
                for (int r = 0; r < 4; ++r) {
                    float f = accS[ct][r] + csv[r] + fmaxf(s1b_r[ct] * acc2[ct][r] + t1b_r[ct], 0.f);
                    fmr[ct] = fmaxf(fmr[ct], f);
                }
            }
        }

        // finish pool across lane groups, then out = Wout @ [featmax; prexyz]
        #pragma unroll
        for (int ct = 0; ct < 4; ++ct) {
            fmr[ct] = fmaxf(fmr[ct], __shfl_xor(fmr[ct], 16));
            fmr[ct] = fmaxf(fmr[ct], __shfl_xor(fmr[ct], 32));
        }
        float po0 = 0.f, po1 = 0.f, po2 = 0.f;
        #pragma unroll
        for (int ct = 0; ct < 4; ++ct) {
            po0 += wo0[ct] * fmr[ct];
            po1 += wo1[ct] * fmr[ct];
            po2 += wo2[ct] * fmr[ct];
        }
        #pragma unroll
        for (int d = 1; d <= 8; d <<= 1) {
            po0 += __shfl_xor(po0, d);
            po1 += __shfl_xor(po1, d);
            po2 += __shfl_xor(po2, d);
        }
        if (l < 3) {
            float p0 = prexyz[(n * 3 + 0) * MT + m];
            float p1 = prexyz[(n * 3 + 1) * MT + m];
            float p2 = prexyz[(n * 3 + 2) * MT + m];
            float o = (l == 0) ? po0 : ((l == 1) ? po1 : po2);
            o += Wout[l * 67 + 64] * p0 + Wout[l * 67 + 65] * p1 + Wout[l * 67 + 66] * p2;
            out[(n * 3 + l) * MT + m] = o;
        }
    }
}

extern "C" void kernel_launch(void* const* d_in, const int* in_sizes, int n_in,
                              void* d_out, int out_size, void* d_ws, size_t ws_size,
                              hipStream_t stream) {
    const float* q    = (const float*)d_in[0];
    const float* srgb = (const float*)d_in[1];
    const float* sxyz = (const float*)d_in[2];
    const float* pxyz = (const float*)d_in[3];
    const float* mask = (const float*)d_in[4];
    const float* W0   = (const float*)d_in[5];
    const float* g0   = (const float*)d_in[6];
    const float* b0   = (const float*)d_in[7];
    const float* m0   = (const float*)d_in[8];
    const float* v0   = (const float*)d_in[9];
    const float* W1a  = (const float*)d_in[10];
    const float* g1a  = (const float*)d_in[11];
    const float* b1a  = (const float*)d_in[12];
    const float* m1a  = (const float*)d_in[13];
    const float* v1a  = (const float*)d_in[14];
    const float* W1b  = (const float*)d_in[15];
    const float* g1b  = (const float*)d_in[16];
    const float* b1b  = (const float*)d_in[17];
    const float* m1b  = (const float*)d_in[18];
    const float* v1b  = (const float*)d_in[19];
    const float* Wsk  = (const float*)d_in[20];
    const float* Wout = (const float*)d_in[21];
    float* out = (float*)d_out;

    hipLaunchKernelGGL(ctx_fused, dim3(300, 2), dim3(256), 0, stream,
        q, srgb, sxyz, pxyz, mask,
        W0, g0, b0, m0, v0,
        W1a, g1a, b1a, m1a, v1a,
        W1b, g1b, b1b, m1b, v1b,
        Wsk, Wout, out);
}